// Round 8
// baseline (1653.422 us; speedup 1.0000x reference)
//
#include <hip/hip_runtime.h>
#include <hip/hip_bf16.h>

#define IN_F 4096
#define OUT_F 11008

typedef __bf16 bf16_t;
typedef bf16_t bf16x8 __attribute__((ext_vector_type(8)));
typedef float f32x4 __attribute__((ext_vector_type(4)));
typedef unsigned int u32;

// ============================ pass 1a: x f32 -> bf16 ============================
__global__ __launch_bounds__(256) void cvt_x_kernel(const float* __restrict__ x,
                                                    bf16_t* __restrict__ xb) {
    size_t i = ((size_t)blockIdx.x * 256 + threadIdx.x) * 8;
    f32x4 v0 = *(const f32x4*)(x + i);
    f32x4 v1 = *(const f32x4*)(x + i + 4);
    bf16x8 h;
    h[0]=(bf16_t)v0[0]; h[1]=(bf16_t)v0[1]; h[2]=(bf16_t)v0[2]; h[3]=(bf16_t)v0[3];
    h[4]=(bf16_t)v1[0]; h[5]=(bf16_t)v1[1]; h[6]=(bf16_t)v1[2]; h[7]=(bf16_t)v1[3];
    *(bf16x8*)(xb + i) = h;
}

// ============ pass 1b: dequant qweight -> Wt[n][k] bf16 (B^T layout) ============
__global__ __launch_bounds__(256) void dequant_kernel(const int* __restrict__ qweight,
                                                      const float* __restrict__ scales,
                                                      const int* __restrict__ qzeros,
                                                      bf16_t* __restrict__ wt) {
    const int n   = blockIdx.x * 256 + threadIdx.x;
    const int kw0 = blockIdx.y * 4;
    const int g   = kw0 >> 4;
    const float s  = scales[(size_t)g * OUT_F + n];
    const int   zw = qzeros[(size_t)g * (OUT_F / 8) + (n >> 3)];
    const float nsz = -s * (float)(((zw >> ((n & 7) * 4)) & 0xF) + 1);
    bf16_t* dst = wt + (size_t)n * IN_F + kw0 * 8;
    #pragma unroll
    for (int j = 0; j < 4; ++j) {
        const int w = qweight[(size_t)(kw0 + j) * OUT_F + n];
        bf16x8 h;
        #pragma unroll
        for (int b = 0; b < 8; ++b)
            h[b] = (bf16_t)fmaf((float)((w >> (4 * b)) & 0xF), s, nsz);
        *(bf16x8*)(dst + j * 8) = h;
    }
}

// ================== pass 2: 256x256 8-phase bf16 B^T GEMM ==================
// R7: R6's one-phase-ahead schedule + minimal addressing to fit the
// 128 arch-VGPR cap (acc=128 AGPR fixed; 512thr => 2 waves/SIMD => 256 total).
// - 4 persistent LDS byte pointers; all ds_reads = ptr + compile-time imm.
// - 4 persistent 64-bit global pointers; stages indexed by uniform koff only.
// - reads/phase 8/4/4/8, each frag-set read >=1 phase before consumption
//   (compiler emits counted lgkm waits -> reads drain under MFMA).
// - stages 0/2/4/2 per K-tile; vmcnt(2) at ph2/ph6-end confirms the next
//   buffer one phase before its first reader (vmcnt(0) on last iteration).

#define NI (IN_F / 128)   // 32 iterations, 64 K-tiles

__global__ __launch_bounds__(512, 2) void gemm_8ph(const bf16_t* __restrict__ A,
                                                   const bf16_t* __restrict__ B,
                                                   float* __restrict__ C) {
    __shared__ __align__(16) bf16_t smemA[2 * 2 * 128 * 64];   // 64 KiB
    __shared__ __align__(16) bf16_t smemB[2 * 2 * 128 * 64];   // 64 KiB

    const int tid  = threadIdx.x;
    const int lane = tid & 63;
    const int wid  = tid >> 6;      // 0..7
    const int wr   = wid >> 2;      // 0..1  (M half)
    const int wc   = wid & 3;       // 0..3  (N quarter)

    // bijective XCD swizzle: nwg = 1376 = 8*172
    const int bid = blockIdx.x;
    const int swz = (bid & 7) * 172 + (bid >> 3);
    const int bx = swz % 43;
    const int by = swz / 43;
    const int m0 = by * 256;
    const int n0 = bx * 256;

    // staging map: linear LDS slot -> inverse-swizzled global offset (elements)
    int offg0, offg1;
    {
        int L0 = tid * 16;
        int p0 = L0 ^ (((L0 >> 7) & 7) << 4);
        offg0 = (p0 >> 7) * IN_F + ((p0 & 127) >> 1);
        int L1 = (512 + tid) * 16;
        int p1 = L1 ^ (((L1 >> 7) & 7) << 4);
        offg1 = (p1 >> 7) * IN_F + ((p1 & 127) >> 1);
    }

    // fragment-read swizzled column byte offsets within a 128B row
    const int xm = (lane & 7) << 4;
    const int arow = lane & 15;
    const int colk0 = (((lane >> 4) * 16)) ^ xm;
    const int colk1 = ((64) + ((lane >> 4) * 16)) ^ xm;

    // persistent LDS read pointers (all ds_reads use + compile-time imm)
    const char* aP0 = (const char*)smemA + wr * 16384 + arow * 128 + colk0;
    const char* aP1 = (const char*)smemA + wr * 16384 + arow * 128 + colk1;
    const char* bP0 = (const char*)smemB + (wc >> 1) * 16384 + ((wc & 1) * 64 + arow) * 128 + colk0;
    const char* bP1 = (const char*)smemB + (wc >> 1) * 16384 + ((wc & 1) * 64 + arow) * 128 + colk1;

    // persistent global stage pointers
    const bf16_t* gA0 = A + (size_t)m0 * IN_F + offg0;
    const bf16_t* gA1 = A + (size_t)m0 * IN_F + offg1;
    const bf16_t* gB0 = B + (size_t)n0 * IN_F + offg0;
    const bf16_t* gB1 = B + (size_t)n0 * IN_F + offg1;

    // LDS stage destination bases
    char* sA = (char*)smemA + wid * 1024;
    char* sB = (char*)smemB + wid * 1024;

#define STAGE_G(gp0, gp1, sbase, buf, half, koff)                                          \
    do {                                                                                   \
        __builtin_amdgcn_global_load_lds(                                                  \
            (const __attribute__((address_space(1))) u32*)((gp0) + (half) * (128 * IN_F) + (koff)), \
            (__attribute__((address_space(3))) u32*)((sbase) + (buf) * 32768 + (half) * 16384),     \
            16, 0, 0);                                                                     \
        __builtin_amdgcn_global_load_lds(                                                  \
            (const __attribute__((address_space(1))) u32*)((gp1) + (half) * (128 * IN_F) + (koff)), \
            (__attribute__((address_space(3))) u32*)((sbase) + (buf) * 32768 + (half) * 16384 + 8192), \
            16, 0, 0);                                                                     \
    } while (0)

#define STAGE_A(buf, half, koff) STAGE_G(gA0, gA1, sA, buf, half, koff)
#define STAGE_B(buf, half, koff) STAGE_G(gB0, gB1, sB, buf, half, koff)

// 8 ds_read_b128: A fragments, m-tiles mg..mg+3 (imm = buf*32768 + mt*2048)
#define RD_A(dst, buf, mg)                                                                 \
    _Pragma("unroll") for (int mm = 0; mm < 4; ++mm) {                                     \
        dst[mm * 2 + 0] = *(const bf16x8*)(aP0 + (buf) * 32768 + ((mg) + mm) * 2048);      \
        dst[mm * 2 + 1] = *(const bf16x8*)(aP1 + (buf) * 32768 + ((mg) + mm) * 2048);      \
    }

// 4 ds_read_b128: B pair fragments, n-tiles P*2..P*2+1
#define RD_B(dst, buf, P)                                                                  \
    _Pragma("unroll") for (int nn = 0; nn < 2; ++nn) {                                     \
        dst[nn * 2 + 0] = *(const bf16x8*)(bP0 + (buf) * 32768 + ((P) * 2 + nn) * 2048);   \
        dst[nn * 2 + 1] = *(const bf16x8*)(bP1 + (buf) * 32768 + ((P) * 2 + nn) * 2048);   \
    }

// 16 MFMA: one quadrant (4 m x 2 n x 2 ks)
#define MFMA_Q(aArr, bArr, mbase, nbase)                                                   \
    __builtin_amdgcn_s_setprio(1);                                                         \
    _Pragma("unroll") for (int mm = 0; mm < 4; ++mm)                                       \
    _Pragma("unroll") for (int nn = 0; nn < 2; ++nn)                                       \
    _Pragma("unroll") for (int ks = 0; ks < 2; ++ks)                                       \
        acc[(mbase) + mm][(nbase) + nn] = __builtin_amdgcn_mfma_f32_16x16x32_bf16(         \
            aArr[mm * 2 + ks], bArr[nn * 2 + ks], acc[(mbase) + mm][(nbase) + nn],         \
            0, 0, 0);                                                                      \
    __builtin_amdgcn_s_setprio(0);

#define BAR() __builtin_amdgcn_s_barrier()
#define VMCNT8() asm volatile("s_waitcnt vmcnt(8)" ::: "memory")
#define VMCNT2() asm volatile("s_waitcnt vmcnt(2)" ::: "memory")
#define VMCNT0() asm volatile("s_waitcnt vmcnt(0)" ::: "memory")

    f32x4 acc[8][4];
    #pragma unroll
    for (int m = 0; m < 8; ++m)
        #pragma unroll
        for (int n = 0; n < 4; ++n)
            acc[m][n] = (f32x4)0.0f;

    bf16x8 aM0[8], aM1[8], b01[4], b23[4];

    // prologue: stage T0 (buf0) then T1 (buf1); confirm T0; preload ph1 frags
    STAGE_A(0, 0, 0);  STAGE_A(0, 1, 0);
    STAGE_B(0, 0, 0);  STAGE_B(0, 1, 0);
    STAGE_A(1, 0, 64); STAGE_A(1, 1, 64);
    STAGE_B(1, 0, 64); STAGE_B(1, 1, 64);
    VMCNT8();          // T0's 8 loads retired (T1's 8 in flight)
    BAR();
    RD_B(b01, 0, 0);
    RD_A(aM0, 0, 0);

    for (int i = 0; i < NI; ++i) {
        const int  kn = i * 128 + 128;  // K-offset of tile T+2 (buf0); T+3 = kn+64
        const bool nl = (i + 1 < NI);

        // ---- ph1 (M0,N01,buf0): read aM1(buf0)
        RD_A(aM1, 0, 4);
        BAR();
        MFMA_Q(aM0, b01, 0, 0);
        BAR();
        // ---- ph2 (M1,N01,buf0): read b23(buf0); stage A(T+2)h0; confirm buf1 tile
        RD_B(b23, 0, 1);
        if (nl) STAGE_A(0, 0, kn);
        BAR();
        MFMA_Q(aM1, b01, 4, 0);
        if (nl) VMCNT2(); else VMCNT0();
        BAR();
        // ---- ph3 (M0,N23,buf0): read b01(buf1); stage A(T+2)h1 + B(T+2)h0
        RD_B(b01, 1, 0);
        if (nl) { STAGE_A(0, 1, kn); STAGE_B(0, 0, kn); }
        BAR();
        MFMA_Q(aM0, b23, 0, 2);
        BAR();
        // ---- ph4 (M1,N23,buf0): read aM0(buf1); stage B(T+2)h1
        RD_A(aM0, 1, 0);
        if (nl) STAGE_B(0, 1, kn);
        BAR();
        MFMA_Q(aM1, b23, 4, 2);
        BAR();
        // ---- ph5 (M0,N01,buf1): read aM1(buf1)
        RD_A(aM1, 1, 4);
        BAR();
        MFMA_Q(aM0, b01, 0, 0);
        BAR();
        // ---- ph6 (M1,N01,buf1): read b23(buf1); stage A(T+3)h0; confirm buf0 tile
        RD_B(b23, 1, 1);
        if (nl) STAGE_A(1, 0, kn + 64);
        BAR();
        MFMA_Q(aM1, b01, 4, 0);
        VMCNT2();
        BAR();
        // ---- ph7 (M0,N23,buf1): read b01(buf0,next); stage A(T+3)h1 + B(T+3)h0
        if (nl) {
            RD_B(b01, 0, 0);
            STAGE_A(1, 1, kn + 64); STAGE_B(1, 0, kn + 64);
        }
        BAR();
        MFMA_Q(aM0, b23, 0, 2);
        BAR();
        // ---- ph8 (M1,N23,buf1): read aM0(buf0,next); stage B(T+3)h1
        if (nl) {
            RD_A(aM0, 0, 0);
            STAGE_B(1, 1, kn + 64);
        }
        BAR();
        MFMA_Q(aM1, b23, 4, 2);
        BAR();
    }

    // epilogue: C/D layout col = lane&15, row = (lane>>4)*4 + r
    const int cn  = lane & 15;
    const int cr4 = (lane >> 4) * 4;
    #pragma unroll
    for (int m = 0; m < 8; ++m) {
        #pragma unroll
        for (int r = 0; r < 4; ++r) {
            const int grow = m0 + wr * 128 + m * 16 + cr4 + r;
            float* orow = C + (size_t)grow * OUT_F + n0 + wc * 64 + cn;
            #pragma unroll
            for (int n = 0; n < 4; ++n)
                orow[n * 16] = acc[m][n][r];
        }
    }
}

// ===================== fallback: fused kernel (R0 structure) =====================
#define BMf 128
#define BNf 128
#define BKf 32
#define LDPF 40

__global__ __launch_bounds__(256, 2) void gptq_gemm_fused(
    const float* __restrict__ x, const int* __restrict__ qweight,
    const float* __restrict__ scales, const int* __restrict__ qzeros,
    float* __restrict__ out)
{
    __shared__ bf16_t As[BMf * LDPF];
    __shared__ bf16_t Bs[BNf * LDPF];
    const int tid = threadIdx.x, lane = tid & 63, wid = tid >> 6;
    const int wr = wid >> 1, wc = wid & 1;
    const int m0 = blockIdx.y * BMf, n0 = blockIdx.x * BNf;
    const int a_row = tid >> 2, a_slot = tid & 3;
    const int b_k8l = tid >> 7, b_n = tid & 127;

    f32x4 acc[4][4];
    #pragma unroll
    for (int i = 0; i < 4; ++i)
        #pragma unroll
        for (int j = 0; j < 4; ++j) acc[i][j] = (f32x4)0.0f;

    for (int kt = 0; kt < IN_F / BKf; ++kt) {
        const int k0 = kt * BKf;
        const int g  = k0 >> 7;
        __syncthreads();
        #pragma unroll
        for (int p = 0; p < 2; ++p) {
            const int row = a_row + p * 64;
            const float* src = x + (size_t)(m0 + row) * IN_F + k0 + a_slot * 8;
            f32x4 v0 = *(const f32x4*)src;
            f32x4 v1 = *(const f32x4*)(src + 4);
            bf16x8 h;
            h[0]=(bf16_t)v0[0]; h[1]=(bf16_t)v0[1]; h[2]=(bf16_t)v0[2]; h[3]=(bf16_t)v0[3];
            h[4]=(bf16_t)v1[0]; h[5]=(bf16_t)v1[1]; h[6]=(bf16_t)v1[2]; h[7]=(bf16_t)v1[3];
            *(bf16x8*)(&As[row * LDPF + a_slot * 8]) = h;
        }
        {
            const int gn = n0 + b_n;
            const float s  = scales[(size_t)g * OUT_F + gn];
            const int   zw = qzeros[(size_t)g * (OUT_F / 8) + (gn >> 3)];
            const float sz = s * (float)(((zw >> ((gn & 7) * 4)) & 0xF) + 1);
            #pragma unroll
            for (int p = 0; p < 2; ++p) {
                const int k8l = b_k8l + p * 2;
                const int w = qweight[(size_t)(k0 / 8 + k8l) * OUT_F + gn];
                bf16x8 h;
                #pragma unroll
                for (int j = 0; j < 8; ++j)
                    h[j] = (bf16_t)fmaf((float)((w >> (4 * j)) & 0xF), s, -sz);
                *(bf16x8*)(&Bs[b_n * LDPF + k8l * 8]) = h;
            }
        }
        __syncthreads();
        bf16x8 af[4], bfr[4];
        #pragma unroll
        for (int m = 0; m < 4; ++m)
            af[m] = *(const bf16x8*)(&As[(wr * 64 + m * 16 + (lane & 15)) * LDPF + (lane >> 4) * 8]);
        #pragma unroll
        for (int n = 0; n < 4; ++n)
            bfr[n] = *(const bf16x8*)(&Bs[(wc * 64 + n * 16 + (lane & 15)) * LDPF + (lane >> 4) * 8]);
        #pragma unroll
        for (int m = 0; m < 4; ++m)
            #pragma unroll
            for (int n = 0; n < 4; ++n)
                acc[m][n] = __builtin_amdgcn_mfma_f32_16x16x32_bf16(af[m], bfr[n], acc[m][n], 0, 0, 0);
    }
    const int cn = lane & 15, cr4 = (lane >> 4) * 4;
    #pragma unroll
    for (int m = 0; m < 4; ++m)
        #pragma unroll
        for (int r = 0; r < 4; ++r) {
            const int grow = m0 + wr * 64 + m * 16 + cr4 + r;
            float* orow = out + (size_t)grow * OUT_F + n0 + wc * 64 + cn;
            #pragma unroll
            for (int n = 0; n < 4; ++n) orow[n * 16] = acc[m][n][r];
        }
}

extern "C" void kernel_launch(void* const* d_in, const int* in_sizes, int n_in,
                              void* d_out, int out_size, void* d_ws, size_t ws_size,
                              hipStream_t stream) {
    const float* x       = (const float*)d_in[0];
    const int*   qweight = (const int*)d_in[1];
    const float* scales  = (const float*)d_in[2];
    const int*   qzeros  = (const int*)d_in[3];
    float* out = (float*)d_out;

    const int M = in_sizes[0] / IN_F;                       // 8192
    const size_t xb_bytes = (size_t)M * IN_F * 2;
    const size_t wt_bytes = (size_t)IN_F * OUT_F * 2;

    if (ws_size >= xb_bytes + wt_bytes && (M % 256) == 0) {
        bf16_t* xb = (bf16_t*)d_ws;
        bf16_t* wt = (bf16_t*)((char*)d_ws + xb_bytes);
        cvt_x_kernel<<<dim3((M * IN_F) / (256 * 8)), dim3(256), 0, stream>>>(x, xb);
        dequant_kernel<<<dim3(OUT_F / 256, IN_F / 32), dim3(256), 0, stream>>>(
            qweight, scales, qzeros, wt);
        const int nwg = (OUT_F / 256) * (M / 256);          // 43*32 = 1376
        gemm_8ph<<<dim3(nwg), dim3(512), 0, stream>>>(xb, wt, out);
    } else {
        gptq_gemm_fused<<<dim3(OUT_F / BNf, M / BMf), dim3(256), 0, stream>>>(
            x, qweight, scales, qzeros, out);
    }
}

// Round 9
// 834.453 us; speedup vs baseline: 1.9814x; 1.9814x over previous
//
#include <hip/hip_runtime.h>
#include <hip/hip_bf16.h>

#define IN_F 4096
#define OUT_F 11008

typedef __bf16 bf16_t;
typedef bf16_t bf16x8 __attribute__((ext_vector_type(8)));
typedef float f32x4 __attribute__((ext_vector_type(4)));
typedef unsigned int u32;

// ============================ pass 1a: x f32 -> bf16 ============================
__global__ __launch_bounds__(256) void cvt_x_kernel(const float* __restrict__ x,
                                                    bf16_t* __restrict__ xb) {
    size_t i = ((size_t)blockIdx.x * 256 + threadIdx.x) * 8;
    f32x4 v0 = *(const f32x4*)(x + i);
    f32x4 v1 = *(const f32x4*)(x + i + 4);
    bf16x8 h;
    h[0]=(bf16_t)v0[0]; h[1]=(bf16_t)v0[1]; h[2]=(bf16_t)v0[2]; h[3]=(bf16_t)v0[3];
    h[4]=(bf16_t)v1[0]; h[5]=(bf16_t)v1[1]; h[6]=(bf16_t)v1[2]; h[7]=(bf16_t)v1[3];
    *(bf16x8*)(xb + i) = h;
}

// ============ pass 1b: dequant qweight -> Wt[n][k] bf16 (B^T layout) ============
__global__ __launch_bounds__(256) void dequant_kernel(const int* __restrict__ qweight,
                                                      const float* __restrict__ scales,
                                                      const int* __restrict__ qzeros,
                                                      bf16_t* __restrict__ wt) {
    const int n   = blockIdx.x * 256 + threadIdx.x;
    const int kw0 = blockIdx.y * 4;
    const int g   = kw0 >> 4;
    const float s  = scales[(size_t)g * OUT_F + n];
    const int   zw = qzeros[(size_t)g * (OUT_F / 8) + (n >> 3)];
    const float nsz = -s * (float)(((zw >> ((n & 7) * 4)) & 0xF) + 1);
    bf16_t* dst = wt + (size_t)n * IN_F + kw0 * 8;
    #pragma unroll
    for (int j = 0; j < 4; ++j) {
        const int w = qweight[(size_t)(kw0 + j) * OUT_F + n];
        bf16x8 h;
        #pragma unroll
        for (int b = 0; b < 8; ++b)
            h[b] = (bf16_t)fmaf((float)((w >> (4 * b)) & 0xF), s, nsz);
        *(bf16x8*)(dst + j * 8) = h;
    }
}

// ================== pass 2: 256x256 8-phase bf16 B^T GEMM ==================
// R8: ONE barrier per phase. Per-wave order: reads -> stage -> MFMA
// (compiler-counted lgkm waits only) -> [vmcnt] -> barrier. Waves free-run
// inside the phase window so one wave's MFMA hides its SIMD-partner's
// ds_reads (cross-wave overlap; lockstep 2-barrier version pinned at 38%).
// 16 frag registers (aR shared M0/M1, b01, b23) — fits 128 arch-VGPR cap.
// Stage ring (each stage >=1 barrier after its region's last reader, whose
// reads are drained by that phase's own MFMA before the barrier):
//   ph1:A(1,1)  ph3:B(0,0)  ph4:A(0,0)  ph5:A(0,1)  ph6:B(0,1)
//   ph7:B(1,0)  ph8:B(1,1)+A(1,0)
// Confirms: VMCNT4@ph4 (covers all stages <= prev ph1 incl. A(1,1));
//           VMCNT6@ph8 (covers all stages <= ph6 => T2 complete).

#define NI (IN_F / 128)   // 32 iterations, 64 K-tiles

__global__ __launch_bounds__(512, 2) void gemm_8ph(const bf16_t* __restrict__ A,
                                                   const bf16_t* __restrict__ B,
                                                   float* __restrict__ C) {
    __shared__ __align__(16) bf16_t smemA[2 * 2 * 128 * 64];   // 64 KiB
    __shared__ __align__(16) bf16_t smemB[2 * 2 * 128 * 64];   // 64 KiB

    const int tid  = threadIdx.x;
    const int lane = tid & 63;
    const int wid  = tid >> 6;      // 0..7
    const int wr   = wid >> 2;      // 0..1  (M half)
    const int wc   = wid & 3;       // 0..3  (N quarter)

    // bijective XCD swizzle: nwg = 1376 = 8*172
    const int bid = blockIdx.x;
    const int swz = (bid & 7) * 172 + (bid >> 3);
    const int bx = swz % 43;
    const int by = swz / 43;
    const int m0 = by * 256;
    const int n0 = bx * 256;

    // staging map: linear LDS slot -> inverse-swizzled global position
    int lr0, kb0, lr1, kb1;
    {
        int L0 = tid * 16;
        int p0 = L0 ^ (((L0 >> 7) & 7) << 4);
        lr0 = p0 >> 7; kb0 = (p0 & 127) >> 1;
        int L1 = (512 + tid) * 16;
        int p1 = L1 ^ (((L1 >> 7) & 7) << 4);
        lr1 = p1 >> 7; kb1 = (p1 & 127) >> 1;
    }

    // fragment-read swizzled column byte offsets within a 128B row
    const int xm = (lane & 7) << 4;
    const int arow = lane & 15;
    int colk[2];
    #pragma unroll
    for (int ks = 0; ks < 2; ++ks)
        colk[ks] = ((ks * 64) + ((lane >> 4) * 16)) ^ xm;

#define STAGE(smem, buf, half, src, rbase, koff)                                           \
    do {                                                                                   \
        const bf16_t* g0_ = (src) + (size_t)((rbase) + lr0) * IN_F + (koff) + kb0;         \
        __builtin_amdgcn_global_load_lds(                                                  \
            (const __attribute__((address_space(1))) u32*)g0_,                             \
            (__attribute__((address_space(3))) u32*)((char*)(smem) + (buf) * 32768 +       \
                                                     (half) * 16384 + wid * 1024),         \
            16, 0, 0);                                                                     \
        const bf16_t* g1_ = (src) + (size_t)((rbase) + lr1) * IN_F + (koff) + kb1;         \
        __builtin_amdgcn_global_load_lds(                                                  \
            (const __attribute__((address_space(1))) u32*)g1_,                             \
            (__attribute__((address_space(3))) u32*)((char*)(smem) + (buf) * 32768 +       \
                                                     (half) * 16384 + 8192 + wid * 1024),  \
            16, 0, 0);                                                                     \
    } while (0)

#define STAGE_A(buf, half, koff) STAGE(smemA, buf, half, A, m0 + (half) * 128, koff)
#define STAGE_B(buf, half, koff) STAGE(smemB, buf, half, B, n0 + (half) * 128, koff)

// 8 ds_read_b128 -> dst[8] : A fragments (4 m-tiles x 2 k-slices)
#define LOAD_A_FRAGS(dst, buf, mbase)                                                      \
    _Pragma("unroll") for (int mm = 0; mm < 4; ++mm)                                       \
    _Pragma("unroll") for (int ks = 0; ks < 2; ++ks)                                       \
        dst[mm * 2 + ks] = *(const bf16x8*)((const char*)smemA + (buf) * 32768 +           \
            wr * 16384 + (((mbase) + mm) * 16 + arow) * 128 + colk[ks]);

// 4 ds_read_b128 -> dst[4] : B pair fragments (2 n-tiles x 2 k-slices), P in {0,1}
#define LOAD_B_PAIR(dst, buf, P)                                                           \
    _Pragma("unroll") for (int nn = 0; nn < 2; ++nn)                                       \
    _Pragma("unroll") for (int ks = 0; ks < 2; ++ks)                                       \
        dst[nn * 2 + ks] = *(const bf16x8*)((const char*)smemB + (buf) * 32768 +           \
            (wc >> 1) * 16384 + ((wc & 1) * 64 + ((P) * 2 + nn) * 16 + arow) * 128 +       \
            colk[ks]);

// 16 MFMA: one quadrant (4 m x 2 n x 2 ks)
#define MFMA_Q(aArr, bArr, mbase, nbase)                                                   \
    __builtin_amdgcn_s_setprio(1);                                                         \
    _Pragma("unroll") for (int mm = 0; mm < 4; ++mm)                                       \
    _Pragma("unroll") for (int nn = 0; nn < 2; ++nn)                                       \
    _Pragma("unroll") for (int ks = 0; ks < 2; ++ks)                                       \
        acc[(mbase) + mm][(nbase) + nn] = __builtin_amdgcn_mfma_f32_16x16x32_bf16(         \
            aArr[mm * 2 + ks], bArr[nn * 2 + ks], acc[(mbase) + mm][(nbase) + nn],         \
            0, 0, 0);                                                                      \
    __builtin_amdgcn_s_setprio(0);

#define BAR() __builtin_amdgcn_s_barrier()
#define VMCNT6() asm volatile("s_waitcnt vmcnt(6)" ::: "memory")
#define VMCNT4() asm volatile("s_waitcnt vmcnt(4)" ::: "memory")
#define VMCNT0() asm volatile("s_waitcnt vmcnt(0)" ::: "memory")

    f32x4 acc[8][4];
    #pragma unroll
    for (int m = 0; m < 8; ++m)
        #pragma unroll
        for (int n = 0; n < 4; ++n)
            acc[m][n] = (f32x4)0.0f;

    bf16x8 aR[8], b01[4], b23[4];

    // prologue: T0 full (8 loads) + T1's B(1,0),B(1,1),A(1,0) (6 loads).
    // A(1,1) is staged by ph1 of iteration 0 (steady-state shape).
    STAGE_A(0, 0, 0);  STAGE_A(0, 1, 0);
    STAGE_B(0, 0, 0);  STAGE_B(0, 1, 0);
    STAGE_B(1, 0, 64); STAGE_B(1, 1, 64);
    STAGE_A(1, 0, 64);
    VMCNT6();          // T0's 8 loads landed; 6 T1 loads in flight
    BAR();

    for (int i = 0; i < NI; ++i) {
        const int  kc = i * 128;        // T0 in buf0; T1 = kc+64 in buf1
        const int  kn = kc + 128;       // T2 in buf0; T3 = kn+64 in buf1
        const bool nl = (i + 1 < NI);

        // ---- ph1: reads A(M0)+b01 (12); stage A(1,1)(T1); MFMA(M0,N01,buf0)
        LOAD_A_FRAGS(aR, 0, 0);
        LOAD_B_PAIR(b01, 0, 0);
        STAGE_A(1, 1, kc + 64);
        MFMA_Q(aR, b01, 0, 0);
        BAR();
        // ---- ph2: reads b23 (4); MFMA(M0,N23,buf0)
        LOAD_B_PAIR(b23, 0, 1);
        MFMA_Q(aR, b23, 0, 2);
        BAR();
        // ---- ph3: reads A(M1) (8, reuse regs); stage B(0,0)(T2); MFMA(M1,N01)
        LOAD_A_FRAGS(aR, 0, 4);
        if (nl) STAGE_B(0, 0, kn);
        MFMA_Q(aR, b01, 4, 0);
        BAR();
        // ---- ph4: stage A(0,0)(T2); MFMA(M1,N23); confirm T1 complete
        if (nl) STAGE_A(0, 0, kn);
        MFMA_Q(aR, b23, 4, 2);
        if (nl) VMCNT4(); else VMCNT0();
        BAR();
        // ---- ph5: reads A(M0)+b01 (12, buf1); stage A(0,1)(T2); MFMA(M0,N01,buf1)
        LOAD_A_FRAGS(aR, 1, 0);
        LOAD_B_PAIR(b01, 1, 0);
        if (nl) STAGE_A(0, 1, kn);
        MFMA_Q(aR, b01, 0, 0);
        BAR();
        // ---- ph6: reads b23 (4); stage B(0,1)(T2); MFMA(M0,N23,buf1)
        LOAD_B_PAIR(b23, 1, 1);
        if (nl) STAGE_B(0, 1, kn);
        MFMA_Q(aR, b23, 0, 2);
        BAR();
        // ---- ph7: reads A(M1) (8); stage B(1,0)(T3); MFMA(M1,N01,buf1)
        LOAD_A_FRAGS(aR, 1, 4);
        if (nl) STAGE_B(1, 0, kn + 64);
        MFMA_Q(aR, b01, 4, 0);
        BAR();
        // ---- ph8: stage B(1,1)+A(1,0)(T3); MFMA(M1,N23,buf1); confirm T2
        if (nl) { STAGE_B(1, 1, kn + 64); STAGE_A(1, 0, kn + 64); }
        MFMA_Q(aR, b23, 4, 2);
        if (nl) VMCNT6();
        BAR();
    }

    // epilogue: C/D layout col = lane&15, row = (lane>>4)*4 + r
    const int cn  = lane & 15;
    const int cr4 = (lane >> 4) * 4;
    #pragma unroll
    for (int m = 0; m < 8; ++m) {
        #pragma unroll
        for (int r = 0; r < 4; ++r) {
            const int grow = m0 + wr * 128 + m * 16 + cr4 + r;
            float* orow = C + (size_t)grow * OUT_F + n0 + wc * 64 + cn;
            #pragma unroll
            for (int n = 0; n < 4; ++n)
                orow[n * 16] = acc[m][n][r];
        }
    }
}

// ===================== fallback: fused kernel (R0 structure) =====================
#define BMf 128
#define BNf 128
#define BKf 32
#define LDPF 40

__global__ __launch_bounds__(256, 2) void gptq_gemm_fused(
    const float* __restrict__ x, const int* __restrict__ qweight,
    const float* __restrict__ scales, const int* __restrict__ qzeros,
    float* __restrict__ out)
{
    __shared__ bf16_t As[BMf * LDPF];
    __shared__ bf16_t Bs[BNf * LDPF];
    const int tid = threadIdx.x, lane = tid & 63, wid = tid >> 6;
    const int wr = wid >> 1, wc = wid & 1;
    const int m0 = blockIdx.y * BMf, n0 = blockIdx.x * BNf;
    const int a_row = tid >> 2, a_slot = tid & 3;
    const int b_k8l = tid >> 7, b_n = tid & 127;

    f32x4 acc[4][4];
    #pragma unroll
    for (int i = 0; i < 4; ++i)
        #pragma unroll
        for (int j = 0; j < 4; ++j) acc[i][j] = (f32x4)0.0f;

    for (int kt = 0; kt < IN_F / BKf; ++kt) {
        const int k0 = kt * BKf;
        const int g  = k0 >> 7;
        __syncthreads();
        #pragma unroll
        for (int p = 0; p < 2; ++p) {
            const int row = a_row + p * 64;
            const float* src = x + (size_t)(m0 + row) * IN_F + k0 + a_slot * 8;
            f32x4 v0 = *(const f32x4*)src;
            f32x4 v1 = *(const f32x4*)(src + 4);
            bf16x8 h;
            h[0]=(bf16_t)v0[0]; h[1]=(bf16_t)v0[1]; h[2]=(bf16_t)v0[2]; h[3]=(bf16_t)v0[3];
            h[4]=(bf16_t)v1[0]; h[5]=(bf16_t)v1[1]; h[6]=(bf16_t)v1[2]; h[7]=(bf16_t)v1[3];
            *(bf16x8*)(&As[row * LDPF + a_slot * 8]) = h;
        }
        {
            const int gn = n0 + b_n;
            const float s  = scales[(size_t)g * OUT_F + gn];
            const int   zw = qzeros[(size_t)g * (OUT_F / 8) + (gn >> 3)];
            const float sz = s * (float)(((zw >> ((gn & 7) * 4)) & 0xF) + 1);
            #pragma unroll
            for (int p = 0; p < 2; ++p) {
                const int k8l = b_k8l + p * 2;
                const int w = qweight[(size_t)(k0 / 8 + k8l) * OUT_F + gn];
                bf16x8 h;
                #pragma unroll
                for (int j = 0; j < 8; ++j)
                    h[j] = (bf16_t)fmaf((float)((w >> (4 * j)) & 0xF), s, -sz);
                *(bf16x8*)(&Bs[b_n * LDPF + k8l * 8]) = h;
            }
        }
        __syncthreads();
        bf16x8 af[4], bfr[4];
        #pragma unroll
        for (int m = 0; m < 4; ++m)
            af[m] = *(const bf16x8*)(&As[(wr * 64 + m * 16 + (lane & 15)) * LDPF + (lane >> 4) * 8]);
        #pragma unroll
        for (int n = 0; n < 4; ++n)
            bfr[n] = *(const bf16x8*)(&Bs[(wc * 64 + n * 16 + (lane & 15)) * LDPF + (lane >> 4) * 8]);
        #pragma unroll
        for (int m = 0; m < 4; ++m)
            #pragma unroll
            for (int n = 0; n < 4; ++n)
                acc[m][n] = __builtin_amdgcn_mfma_f32_16x16x32_bf16(af[m], bfr[n], acc[m][n], 0, 0, 0);
    }
    const int cn = lane & 15, cr4 = (lane >> 4) * 4;
    #pragma unroll
    for (int m = 0; m < 4; ++m)
        #pragma unroll
        for (int r = 0; r < 4; ++r) {
            const int grow = m0 + wr * 64 + m * 16 + cr4 + r;
            float* orow = out + (size_t)grow * OUT_F + n0 + wc * 64 + cn;
            #pragma unroll
            for (int n = 0; n < 4; ++n) orow[n * 16] = acc[m][n][r];
        }
}

extern "C" void kernel_launch(void* const* d_in, const int* in_sizes, int n_in,
                              void* d_out, int out_size, void* d_ws, size_t ws_size,
                              hipStream_t stream) {
    const float* x       = (const float*)d_in[0];
    const int*   qweight = (const int*)d_in[1];
    const float* scales  = (const float*)d_in[2];
    const int*   qzeros  = (const int*)d_in[3];
    float* out = (float*)d_out;

    const int M = in_sizes[0] / IN_F;                       // 8192
    const size_t xb_bytes = (size_t)M * IN_F * 2;
    const size_t wt_bytes = (size_t)IN_F * OUT_F * 2;

    if (ws_size >= xb_bytes + wt_bytes && (M % 256) == 0) {
        bf16_t* xb = (bf16_t*)d_ws;
        bf16_t* wt = (bf16_t*)((char*)d_ws + xb_bytes);
        cvt_x_kernel<<<dim3((M * IN_F) / (256 * 8)), dim3(256), 0, stream>>>(x, xb);
        dequant_kernel<<<dim3(OUT_F / 256, IN_F / 32), dim3(256), 0, stream>>>(
            qweight, scales, qzeros, wt);
        const int nwg = (OUT_F / 256) * (M / 256);          // 43*32 = 1376
        gemm_8ph<<<dim3(nwg), dim3(512), 0, stream>>>(xb, wt, out);
    } else {
        gptq_gemm_fused<<<dim3(OUT_F / BNf, M / BMf), dim3(256), 0, stream>>>(
            x, qweight, scales, qzeros, out);
    }
}

// Round 10
// 811.735 us; speedup vs baseline: 2.0369x; 1.0280x over previous
//
#include <hip/hip_runtime.h>
#include <hip/hip_bf16.h>

#define IN_F 4096
#define OUT_F 11008

typedef __bf16 bf16_t;
typedef bf16_t bf16x8 __attribute__((ext_vector_type(8)));
typedef float f32x4 __attribute__((ext_vector_type(4)));
typedef unsigned int u32;

// ============================ pass 1a: x f32 -> bf16 ============================
__global__ __launch_bounds__(256) void cvt_x_kernel(const float* __restrict__ x,
                                                    bf16_t* __restrict__ xb) {
    size_t i = ((size_t)blockIdx.x * 256 + threadIdx.x) * 8;
    f32x4 v0 = __builtin_nontemporal_load((const f32x4*)(x + i));      // read-once
    f32x4 v1 = __builtin_nontemporal_load((const f32x4*)(x + i + 4));
    bf16x8 h;
    h[0]=(bf16_t)v0[0]; h[1]=(bf16_t)v0[1]; h[2]=(bf16_t)v0[2]; h[3]=(bf16_t)v0[3];
    h[4]=(bf16_t)v1[0]; h[5]=(bf16_t)v1[1]; h[6]=(bf16_t)v1[2]; h[7]=(bf16_t)v1[3];
    *(bf16x8*)(xb + i) = h;    // re-read by GEMM: keep cached
}

// ============ pass 1b: dequant qweight -> Wt[n][k] bf16 (B^T layout) ============
__global__ __launch_bounds__(256) void dequant_kernel(const int* __restrict__ qweight,
                                                      const float* __restrict__ scales,
                                                      const int* __restrict__ qzeros,
                                                      bf16_t* __restrict__ wt) {
    const int n   = blockIdx.x * 256 + threadIdx.x;
    const int kw0 = blockIdx.y * 4;
    const int g   = kw0 >> 4;
    const float s  = scales[(size_t)g * OUT_F + n];
    const int   zw = qzeros[(size_t)g * (OUT_F / 8) + (n >> 3)];
    const float nsz = -s * (float)(((zw >> ((n & 7) * 4)) & 0xF) + 1);
    bf16_t* dst = wt + (size_t)n * IN_F + kw0 * 8;
    #pragma unroll
    for (int j = 0; j < 4; ++j) {
        const int w = __builtin_nontemporal_load(&qweight[(size_t)(kw0 + j) * OUT_F + n]); // read-once
        bf16x8 h;
        #pragma unroll
        for (int b = 0; b < 8; ++b)
            h[b] = (bf16_t)fmaf((float)((w >> (4 * b)) & 0xF), s, nsz);
        *(bf16x8*)(dst + j * 8) = h;   // re-read by GEMM: keep cached
    }
}

// ================== pass 2: 256x256 8-phase bf16 B^T GEMM ==================
// R8 structure unchanged (single barrier/phase, 16 frag regs, stage ring
// ph1/ph3/ph4/ph5/ph6/ph7/ph8, VMCNT4@ph4 VMCNT6@ph8).
// R9 single-variable change: C epilogue stores are NON-TEMPORAL so the
// 360 MB write-once output stream stops evicting the A/B panels (157 MB,
// L3-fit) — attacks the measured 1.5 GB FETCH_SIZE (ideal ~0.16 GB).

#define NI (IN_F / 128)   // 32 iterations, 64 K-tiles

__global__ __launch_bounds__(512, 2) void gemm_8ph(const bf16_t* __restrict__ A,
                                                   const bf16_t* __restrict__ B,
                                                   float* __restrict__ C) {
    __shared__ __align__(16) bf16_t smemA[2 * 2 * 128 * 64];   // 64 KiB
    __shared__ __align__(16) bf16_t smemB[2 * 2 * 128 * 64];   // 64 KiB

    const int tid  = threadIdx.x;
    const int lane = tid & 63;
    const int wid  = tid >> 6;      // 0..7
    const int wr   = wid >> 2;      // 0..1  (M half)
    const int wc   = wid & 3;       // 0..3  (N quarter)

    // bijective XCD swizzle: nwg = 1376 = 8*172
    const int bid = blockIdx.x;
    const int swz = (bid & 7) * 172 + (bid >> 3);
    const int bx = swz % 43;
    const int by = swz / 43;
    const int m0 = by * 256;
    const int n0 = bx * 256;

    // staging map: linear LDS slot -> inverse-swizzled global position
    int lr0, kb0, lr1, kb1;
    {
        int L0 = tid * 16;
        int p0 = L0 ^ (((L0 >> 7) & 7) << 4);
        lr0 = p0 >> 7; kb0 = (p0 & 127) >> 1;
        int L1 = (512 + tid) * 16;
        int p1 = L1 ^ (((L1 >> 7) & 7) << 4);
        lr1 = p1 >> 7; kb1 = (p1 & 127) >> 1;
    }

    // fragment-read swizzled column byte offsets within a 128B row
    const int xm = (lane & 7) << 4;
    const int arow = lane & 15;
    int colk[2];
    #pragma unroll
    for (int ks = 0; ks < 2; ++ks)
        colk[ks] = ((ks * 64) + ((lane >> 4) * 16)) ^ xm;

#define STAGE(smem, buf, half, src, rbase, koff)                                           \
    do {                                                                                   \
        const bf16_t* g0_ = (src) + (size_t)((rbase) + lr0) * IN_F + (koff) + kb0;         \
        __builtin_amdgcn_global_load_lds(                                                  \
            (const __attribute__((address_space(1))) u32*)g0_,                             \
            (__attribute__((address_space(3))) u32*)((char*)(smem) + (buf) * 32768 +       \
                                                     (half) * 16384 + wid * 1024),         \
            16, 0, 0);                                                                     \
        const bf16_t* g1_ = (src) + (size_t)((rbase) + lr1) * IN_F + (koff) + kb1;         \
        __builtin_amdgcn_global_load_lds(                                                  \
            (const __attribute__((address_space(1))) u32*)g1_,                             \
            (__attribute__((address_space(3))) u32*)((char*)(smem) + (buf) * 32768 +       \
                                                     (half) * 16384 + 8192 + wid * 1024),  \
            16, 0, 0);                                                                     \
    } while (0)

#define STAGE_A(buf, half, koff) STAGE(smemA, buf, half, A, m0 + (half) * 128, koff)
#define STAGE_B(buf, half, koff) STAGE(smemB, buf, half, B, n0 + (half) * 128, koff)

// 8 ds_read_b128 -> dst[8] : A fragments (4 m-tiles x 2 k-slices)
#define LOAD_A_FRAGS(dst, buf, mbase)                                                      \
    _Pragma("unroll") for (int mm = 0; mm < 4; ++mm)                                       \
    _Pragma("unroll") for (int ks = 0; ks < 2; ++ks)                                       \
        dst[mm * 2 + ks] = *(const bf16x8*)((const char*)smemA + (buf) * 32768 +           \
            wr * 16384 + (((mbase) + mm) * 16 + arow) * 128 + colk[ks]);

// 4 ds_read_b128 -> dst[4] : B pair fragments (2 n-tiles x 2 k-slices), P in {0,1}
#define LOAD_B_PAIR(dst, buf, P)                                                           \
    _Pragma("unroll") for (int nn = 0; nn < 2; ++nn)                                       \
    _Pragma("unroll") for (int ks = 0; ks < 2; ++ks)                                       \
        dst[nn * 2 + ks] = *(const bf16x8*)((const char*)smemB + (buf) * 32768 +           \
            (wc >> 1) * 16384 + ((wc & 1) * 64 + ((P) * 2 + nn) * 16 + arow) * 128 +       \
            colk[ks]);

// 16 MFMA: one quadrant (4 m x 2 n x 2 ks)
#define MFMA_Q(aArr, bArr, mbase, nbase)                                                   \
    __builtin_amdgcn_s_setprio(1);                                                         \
    _Pragma("unroll") for (int mm = 0; mm < 4; ++mm)                                       \
    _Pragma("unroll") for (int nn = 0; nn < 2; ++nn)                                       \
    _Pragma("unroll") for (int ks = 0; ks < 2; ++ks)                                       \
        acc[(mbase) + mm][(nbase) + nn] = __builtin_amdgcn_mfma_f32_16x16x32_bf16(         \
            aArr[mm * 2 + ks], bArr[nn * 2 + ks], acc[(mbase) + mm][(nbase) + nn],         \
            0, 0, 0);                                                                      \
    __builtin_amdgcn_s_setprio(0);

#define BAR() __builtin_amdgcn_s_barrier()
#define VMCNT6() asm volatile("s_waitcnt vmcnt(6)" ::: "memory")
#define VMCNT4() asm volatile("s_waitcnt vmcnt(4)" ::: "memory")
#define VMCNT0() asm volatile("s_waitcnt vmcnt(0)" ::: "memory")

    f32x4 acc[8][4];
    #pragma unroll
    for (int m = 0; m < 8; ++m)
        #pragma unroll
        for (int n = 0; n < 4; ++n)
            acc[m][n] = (f32x4)0.0f;

    bf16x8 aR[8], b01[4], b23[4];

    // prologue: T0 full (8 loads) + T1's B(1,0),B(1,1),A(1,0) (6 loads).
    // A(1,1) is staged by ph1 of iteration 0 (steady-state shape).
    STAGE_A(0, 0, 0);  STAGE_A(0, 1, 0);
    STAGE_B(0, 0, 0);  STAGE_B(0, 1, 0);
    STAGE_B(1, 0, 64); STAGE_B(1, 1, 64);
    STAGE_A(1, 0, 64);
    VMCNT6();          // T0's 8 loads landed; 6 T1 loads in flight
    BAR();

    for (int i = 0; i < NI; ++i) {
        const int  kc = i * 128;        // T0 in buf0; T1 = kc+64 in buf1
        const int  kn = kc + 128;       // T2 in buf0; T3 = kn+64 in buf1
        const bool nl = (i + 1 < NI);

        // ---- ph1: reads A(M0)+b01 (12); stage A(1,1)(T1); MFMA(M0,N01,buf0)
        LOAD_A_FRAGS(aR, 0, 0);
        LOAD_B_PAIR(b01, 0, 0);
        STAGE_A(1, 1, kc + 64);
        MFMA_Q(aR, b01, 0, 0);
        BAR();
        // ---- ph2: reads b23 (4); MFMA(M0,N23,buf0)
        LOAD_B_PAIR(b23, 0, 1);
        MFMA_Q(aR, b23, 0, 2);
        BAR();
        // ---- ph3: reads A(M1) (8, reuse regs); stage B(0,0)(T2); MFMA(M1,N01)
        LOAD_A_FRAGS(aR, 0, 4);
        if (nl) STAGE_B(0, 0, kn);
        MFMA_Q(aR, b01, 4, 0);
        BAR();
        // ---- ph4: stage A(0,0)(T2); MFMA(M1,N23); confirm T1 complete
        if (nl) STAGE_A(0, 0, kn);
        MFMA_Q(aR, b23, 4, 2);
        if (nl) VMCNT4(); else VMCNT0();
        BAR();
        // ---- ph5: reads A(M0)+b01 (12, buf1); stage A(0,1)(T2); MFMA(M0,N01,buf1)
        LOAD_A_FRAGS(aR, 1, 0);
        LOAD_B_PAIR(b01, 1, 0);
        if (nl) STAGE_A(0, 1, kn);
        MFMA_Q(aR, b01, 0, 0);
        BAR();
        // ---- ph6: reads b23 (4); stage B(0,1)(T2); MFMA(M0,N23,buf1)
        LOAD_B_PAIR(b23, 1, 1);
        if (nl) STAGE_B(0, 1, kn);
        MFMA_Q(aR, b23, 0, 2);
        BAR();
        // ---- ph7: reads A(M1) (8); stage B(1,0)(T3); MFMA(M1,N01,buf1)
        LOAD_A_FRAGS(aR, 1, 4);
        if (nl) STAGE_B(1, 0, kn + 64);
        MFMA_Q(aR, b01, 4, 0);
        BAR();
        // ---- ph8: stage B(1,1)+A(1,0)(T3); MFMA(M1,N23,buf1); confirm T2
        if (nl) { STAGE_B(1, 1, kn + 64); STAGE_A(1, 0, kn + 64); }
        MFMA_Q(aR, b23, 4, 2);
        if (nl) VMCNT6();
        BAR();
    }

    // epilogue: C/D layout col = lane&15, row = (lane>>4)*4 + r
    // NON-TEMPORAL stores: C is write-once; keep it out of L3 so A/B stay hot.
    const int cn  = lane & 15;
    const int cr4 = (lane >> 4) * 4;
    #pragma unroll
    for (int m = 0; m < 8; ++m) {
        #pragma unroll
        for (int r = 0; r < 4; ++r) {
            const int grow = m0 + wr * 128 + m * 16 + cr4 + r;
            float* orow = C + (size_t)grow * OUT_F + n0 + wc * 64 + cn;
            #pragma unroll
            for (int n = 0; n < 4; ++n)
                __builtin_nontemporal_store(acc[m][n][r], orow + n * 16);
        }
    }
}

// ===================== fallback: fused kernel (R0 structure) =====================
#define BMf 128
#define BNf 128
#define BKf 32
#define LDPF 40

__global__ __launch_bounds__(256, 2) void gptq_gemm_fused(
    const float* __restrict__ x, const int* __restrict__ qweight,
    const float* __restrict__ scales, const int* __restrict__ qzeros,
    float* __restrict__ out)
{
    __shared__ bf16_t As[BMf * LDPF];
    __shared__ bf16_t Bs[BNf * LDPF];
    const int tid = threadIdx.x, lane = tid & 63, wid = tid >> 6;
    const int wr = wid >> 1, wc = wid & 1;
    const int m0 = blockIdx.y * BMf, n0 = blockIdx.x * BNf;
    const int a_row = tid >> 2, a_slot = tid & 3;
    const int b_k8l = tid >> 7, b_n = tid & 127;

    f32x4 acc[4][4];
    #pragma unroll
    for (int i = 0; i < 4; ++i)
        #pragma unroll
        for (int j = 0; j < 4; ++j) acc[i][j] = (f32x4)0.0f;

    for (int kt = 0; kt < IN_F / BKf; ++kt) {
        const int k0 = kt * BKf;
        const int g  = k0 >> 7;
        __syncthreads();
        #pragma unroll
        for (int p = 0; p < 2; ++p) {
            const int row = a_row + p * 64;
            const float* src = x + (size_t)(m0 + row) * IN_F + k0 + a_slot * 8;
            f32x4 v0 = *(const f32x4*)src;
            f32x4 v1 = *(const f32x4*)(src + 4);
            bf16x8 h;
            h[0]=(bf16_t)v0[0]; h[1]=(bf16_t)v0[1]; h[2]=(bf16_t)v0[2]; h[3]=(bf16_t)v0[3];
            h[4]=(bf16_t)v1[0]; h[5]=(bf16_t)v1[1]; h[6]=(bf16_t)v1[2]; h[7]=(bf16_t)v1[3];
            *(bf16x8*)(&As[row * LDPF + a_slot * 8]) = h;
        }
        {
            const int gn = n0 + b_n;
            const float s  = scales[(size_t)g * OUT_F + gn];
            const int   zw = qzeros[(size_t)g * (OUT_F / 8) + (gn >> 3)];
            const float sz = s * (float)(((zw >> ((gn & 7) * 4)) & 0xF) + 1);
            #pragma unroll
            for (int p = 0; p < 2; ++p) {
                const int k8l = b_k8l + p * 2;
                const int w = qweight[(size_t)(k0 / 8 + k8l) * OUT_F + gn];
                bf16x8 h;
                #pragma unroll
                for (int j = 0; j < 8; ++j)
                    h[j] = (bf16_t)fmaf((float)((w >> (4 * j)) & 0xF), s, -sz);
                *(bf16x8*)(&Bs[b_n * LDPF + k8l * 8]) = h;
            }
        }
        __syncthreads();
        bf16x8 af[4], bfr[4];
        #pragma unroll
        for (int m = 0; m < 4; ++m)
            af[m] = *(const bf16x8*)(&As[(wr * 64 + m * 16 + (lane & 15)) * LDPF + (lane >> 4) * 8]);
        #pragma unroll
        for (int n = 0; n < 4; ++n)
            bfr[n] = *(const bf16x8*)(&Bs[(wc * 64 + n * 16 + (lane & 15)) * LDPF + (lane >> 4) * 8]);
        #pragma unroll
        for (int m = 0; m < 4; ++m)
            #pragma unroll
            for (int n = 0; n < 4; ++n)
                acc[m][n] = __builtin_amdgcn_mfma_f32_16x16x32_bf16(af[m], bfr[n], acc[m][n], 0, 0, 0);
    }
    const int cn = lane & 15, cr4 = (lane >> 4) * 4;
    #pragma unroll
    for (int m = 0; m < 4; ++m)
        #pragma unroll
        for (int r = 0; r < 4; ++r) {
            const int grow = m0 + wr * 64 + m * 16 + cr4 + r;
            float* orow = out + (size_t)grow * OUT_F + n0 + wc * 64 + cn;
            #pragma unroll
            for (int n = 0; n < 4; ++n) orow[n * 16] = acc[m][n][r];
        }
}

extern "C" void kernel_launch(void* const* d_in, const int* in_sizes, int n_in,
                              void* d_out, int out_size, void* d_ws, size_t ws_size,
                              hipStream_t stream) {
    const float* x       = (const float*)d_in[0];
    const int*   qweight = (const int*)d_in[1];
    const float* scales  = (const float*)d_in[2];
    const int*   qzeros  = (const int*)d_in[3];
    float* out = (float*)d_out;

    const int M = in_sizes[0] / IN_F;                       // 8192
    const size_t xb_bytes = (size_t)M * IN_F * 2;
    const size_t wt_bytes = (size_t)IN_F * OUT_F * 2;

    if (ws_size >= xb_bytes + wt_bytes && (M % 256) == 0) {
        bf16_t* xb = (bf16_t*)d_ws;
        bf16_t* wt = (bf16_t*)((char*)d_ws + xb_bytes);
        cvt_x_kernel<<<dim3((M * IN_F) / (256 * 8)), dim3(256), 0, stream>>>(x, xb);
        dequant_kernel<<<dim3(OUT_F / 256, IN_F / 32), dim3(256), 0, stream>>>(
            qweight, scales, qzeros, wt);
        const int nwg = (OUT_F / 256) * (M / 256);          // 43*32 = 1376
        gemm_8ph<<<dim3(nwg), dim3(512), 0, stream>>>(xb, wt, out);
    } else {
        gptq_gemm_fused<<<dim3(OUT_F / BNf, M / BMf), dim3(256), 0, stream>>>(
            x, qweight, scales, qzeros, out);
    }
}